// Round 1
// baseline (3002.756 us; speedup 1.0000x reference)
//
#include <hip/hip_runtime.h>

#define S_LEN 2048
#define B_SZ  2
#define H_DIM 2048
#define NH_   16
#define HN_   128
#define M_TOK (S_LEN * B_SZ)   /* 4096 rows, row = s*B + b */
#define NQKV  (3 * H_DIM)      /* 6144 */

// ---------------------------------------------------------------------------
// C[M,N] = A[M,K] @ W[N,K]^T (+bias).  128x128 tile, BK=16, 256 thr, 8x8 micro.
// All dims here are multiples of 128/16 -> no edge handling.
// ---------------------------------------------------------------------------
__global__ __launch_bounds__(256) void gemm_nt(const float* __restrict__ A,
                                               const float* __restrict__ W,
                                               const float* __restrict__ bias,
                                               float* __restrict__ C,
                                               int M, int N, int K)
{
    __shared__ float As[16][132];   // stored transposed: As[k][m]
    __shared__ float Bs[16][132];   // Bs[k][n]
    const int t  = threadIdx.x;
    const int tx = t & 15, ty = t >> 4;
    const int m0 = blockIdx.y * 128, n0 = blockIdx.x * 128;

    float acc[8][8];
#pragma unroll
    for (int i = 0; i < 8; ++i)
#pragma unroll
        for (int j = 0; j < 8; ++j) acc[i][j] = 0.f;

    for (int k0 = 0; k0 < K; k0 += 16) {
#pragma unroll
        for (int i = 0; i < 2; ++i) {
            int f   = t + i * 256;        // 0..511 -> 512 float4 per operand
            int row = f >> 2;             // 0..127
            int c4  = (f & 3) * 4;        // 0,4,8,12
            float4 va = *(const float4*)&A[(size_t)(m0 + row) * K + k0 + c4];
            As[c4 + 0][row] = va.x; As[c4 + 1][row] = va.y;
            As[c4 + 2][row] = va.z; As[c4 + 3][row] = va.w;
            float4 vb = *(const float4*)&W[(size_t)(n0 + row) * K + k0 + c4];
            Bs[c4 + 0][row] = vb.x; Bs[c4 + 1][row] = vb.y;
            Bs[c4 + 2][row] = vb.z; Bs[c4 + 3][row] = vb.w;
        }
        __syncthreads();
#pragma unroll
        for (int kk = 0; kk < 16; ++kk) {
            float4 a0 = *(const float4*)&As[kk][ty * 4];
            float4 a1 = *(const float4*)&As[kk][64 + ty * 4];
            float4 b0 = *(const float4*)&Bs[kk][tx * 4];
            float4 b1 = *(const float4*)&Bs[kk][64 + tx * 4];
            float a[8] = {a0.x, a0.y, a0.z, a0.w, a1.x, a1.y, a1.z, a1.w};
            float b[8] = {b0.x, b0.y, b0.z, b0.w, b1.x, b1.y, b1.z, b1.w};
#pragma unroll
            for (int i = 0; i < 8; ++i)
#pragma unroll
                for (int j = 0; j < 8; ++j)
                    acc[i][j] = fmaf(a[i], b[j], acc[i][j]);
        }
        __syncthreads();
    }

#pragma unroll
    for (int i = 0; i < 8; ++i) {
        int row = m0 + (i < 4 ? ty * 4 + i : 64 + ty * 4 + i - 4);
#pragma unroll
        for (int jh = 0; jh < 2; ++jh) {
            int col = n0 + (jh == 0 ? tx * 4 : 64 + tx * 4);
            float4 o;
            o.x = acc[i][jh * 4 + 0]; o.y = acc[i][jh * 4 + 1];
            o.z = acc[i][jh * 4 + 2]; o.w = acc[i][jh * 4 + 3];
            if (bias) {
                o.x += bias[col + 0]; o.y += bias[col + 1];
                o.z += bias[col + 2]; o.w += bias[col + 3];
            }
            *(float4*)&C[(size_t)row * N + col] = o;
        }
    }
}

// ---------------------------------------------------------------------------
// Flash-style causal attention, fp32. One block = (b, head, 32-row Q tile).
// qkv is unified [M_TOK][6144]: q at n*384, k at n*384+128, v at n*384+256.
// Q pre-scaled by 1/sqrt(128). Writes ctx in [s,b,h] layout.
// ---------------------------------------------------------------------------
__global__ __launch_bounds__(256) void attn(const float* __restrict__ qkv,
                                            float* __restrict__ ctx)
{
    __shared__ float Qs[32][132];
    __shared__ float Ks[32][132];
    __shared__ float Vs[32][132];
    __shared__ float Sc[32][33];
    __shared__ float mrow[32], lrow[32], crow[32];

    const int t  = threadIdx.x;
    const int qt = blockIdx.x;      // 0..63
    const int n  = blockIdx.y;      // head
    const int b  = blockIdx.z;      // batch
    const int qq0 = qt * 32;
    const float scale = 0.08838834764831845f;   // 1/sqrt(128)

    // load + pre-scale Q tile (32x128 = 1024 float4, 4 per thread)
#pragma unroll
    for (int i = 0; i < 4; ++i) {
        int f   = t + i * 256;
        int row = f >> 5;
        int c   = (f & 31) * 4;
        float4 v = *(const float4*)&qkv[((size_t)((qq0 + row) * B_SZ + b)) * NQKV
                                        + n * 384 + c];
        v.x *= scale; v.y *= scale; v.z *= scale; v.w *= scale;
        *(float4*)&Qs[row][c] = v;
    }
    if (t < 32) { mrow[t] = -1e30f; lrow[t] = 0.f; }

    float acc[4][4];
#pragma unroll
    for (int i = 0; i < 4; ++i)
#pragma unroll
        for (int j = 0; j < 4; ++j) acc[i][j] = 0.f;

    const int r0 = t >> 5;          // 0..7 -> rows r0+8i
    const int kc = t & 31;          // score column
    const int c0 = (t & 31) * 4;    // owned output cols
    __syncthreads();

    for (int kt = 0; kt <= qt; ++kt) {
        // load K,V tiles (32x128 each)
#pragma unroll
        for (int i = 0; i < 4; ++i) {
            int f   = t + i * 256;
            int row = f >> 5;
            int c   = (f & 31) * 4;
            size_t base = ((size_t)((kt * 32 + row) * B_SZ + b)) * NQKV + n * 384 + c;
            *(float4*)&Ks[row][c] = *(const float4*)&qkv[base + 128];
            *(float4*)&Vs[row][c] = *(const float4*)&qkv[base + 256];
        }
        __syncthreads();

        // scores: thread computes S[r0+8i][kc], i<4
        float s[4] = {0.f, 0.f, 0.f, 0.f};
        for (int d = 0; d < 128; d += 4) {
            float4 k4 = *(const float4*)&Ks[kc][d];
#pragma unroll
            for (int i = 0; i < 4; ++i) {
                float4 q4 = *(const float4*)&Qs[r0 + 8 * i][d];
                s[i] += q4.x * k4.x + q4.y * k4.y + q4.z * k4.z + q4.w * k4.w;
            }
        }
#pragma unroll
        for (int i = 0; i < 4; ++i) {
            int r = r0 + 8 * i;
            Sc[r][kc] = (kt * 32 + kc <= qq0 + r) ? s[i] : -1e30f;
        }
        __syncthreads();

        // online softmax, one thread per row
        if (t < 32) {
            int r = t;
            float mold = mrow[r];
            float mx = -1e30f;
            for (int j = 0; j < 32; ++j) mx = fmaxf(mx, Sc[r][j]);
            float mnew = fmaxf(mold, mx);
            float corr = __expf(mold - mnew);   // 0 on first tile
            float sum = 0.f;
            for (int j = 0; j < 32; ++j) {
                float p = __expf(Sc[r][j] - mnew);
                Sc[r][j] = p;
                sum += p;
            }
            lrow[r] = corr * lrow[r] + sum;
            mrow[r] = mnew;
            crow[r] = corr;
        }
        __syncthreads();

        // rescale + PV
#pragma unroll
        for (int i = 0; i < 4; ++i) {
            float cr = crow[r0 + 8 * i];
            acc[i][0] *= cr; acc[i][1] *= cr; acc[i][2] *= cr; acc[i][3] *= cr;
        }
        for (int j = 0; j < 32; ++j) {
            float4 v4 = *(const float4*)&Vs[j][c0];
#pragma unroll
            for (int i = 0; i < 4; ++i) {
                float p = Sc[r0 + 8 * i][j];
                acc[i][0] = fmaf(p, v4.x, acc[i][0]);
                acc[i][1] = fmaf(p, v4.y, acc[i][1]);
                acc[i][2] = fmaf(p, v4.z, acc[i][2]);
                acc[i][3] = fmaf(p, v4.w, acc[i][3]);
            }
        }
        __syncthreads();   // protect Ks/Vs/Sc before next tile
    }

    // epilogue: ctx[(s*B+b)*H + n*128 + c0]
#pragma unroll
    for (int i = 0; i < 4; ++i) {
        int r = r0 + 8 * i;
        float inv = 1.0f / lrow[r];
        float4 o;
        o.x = acc[i][0] * inv; o.y = acc[i][1] * inv;
        o.z = acc[i][2] * inv; o.w = acc[i][3] * inv;
        *(float4*)&ctx[((size_t)((qq0 + r) * B_SZ + b)) * H_DIM + n * HN_ + c0] = o;
    }
}

__global__ void copy_bias(const float* __restrict__ b_dense, float* __restrict__ out)
{
    int t = blockIdx.x * 256 + threadIdx.x;
    if (t < H_DIM) out[(size_t)M_TOK * H_DIM + t] = b_dense[t];
}

extern "C" void kernel_launch(void* const* d_in, const int* in_sizes, int n_in,
                              void* d_out, int out_size, void* d_ws, size_t ws_size,
                              hipStream_t stream)
{
    const float* hs      = (const float*)d_in[0];
    /* d_in[1] attention_mask: compile-time causal, ignored */
    const float* w_qkv   = (const float*)d_in[2];
    const float* b_qkv   = (const float*)d_in[3];
    const float* w_dense = (const float*)d_in[4];
    const float* b_dense = (const float*)d_in[5];
    float* out = (float*)d_out;

    float* qkv = (float*)d_ws;                         // [4096][6144] fp32, 100.7 MB
    float* ctx = qkv + (size_t)M_TOK * NQKV;           // [4096][2048] fp32,  33.6 MB

    // 1) QKV projection + bias -> unified qkv buffer
    gemm_nt<<<dim3(NQKV / 128, M_TOK / 128), 256, 0, stream>>>(
        hs, w_qkv, b_qkv, qkv, M_TOK, NQKV, H_DIM);

    // 2) causal flash attention -> ctx in [s,b,h]
    attn<<<dim3(S_LEN / 32, NH_, B_SZ), 256, 0, stream>>>(qkv, ctx);

    // 3) dense projection (skip_bias_add) -> out[0:M*H]
    gemm_nt<<<dim3(H_DIM / 128, M_TOK / 128), 256, 0, stream>>>(
        ctx, w_dense, nullptr, out, M_TOK, H_DIM, H_DIM);

    // 4) second tuple output: b_dense passthrough
    copy_bias<<<(H_DIM + 255) / 256, 256, 0, stream>>>(b_dense, out);
}

// Round 2
// 615.229 us; speedup vs baseline: 4.8807x; 4.8807x over previous
//
#include <hip/hip_runtime.h>

typedef unsigned short u16;
typedef unsigned int   u32;
typedef __attribute__((ext_vector_type(8))) short bf16x8;   // 8 bf16 = 4 VGPRs
typedef __attribute__((ext_vector_type(4))) float f32x4;

#define S_LEN 2048
#define B_SZ  2
#define H_DIM 2048
#define NH_   16
#define HN_   128
#define M_TOK 4096          /* tokens, row = s*B + b */
#define NQKV  6144

// float -> bf16 round-to-nearest-even
__device__ __forceinline__ u16 f2bf(float f) {
    u32 x = __float_as_uint(f);
    return (u16)((x + 0x7fffu + ((x >> 16) & 1u)) >> 16);
}

// async global->LDS, 16 B per lane; LDS dest = wave-uniform base + lane*16
__device__ __forceinline__ void async16(const void* g, void* l) {
    __builtin_amdgcn_global_load_lds((const __attribute__((address_space(1))) void*)g,
                                     (__attribute__((address_space(3))) void*)l,
                                     16, 0, 0);
}

__global__ __launch_bounds__(256) void cvt_bf16(const float* __restrict__ in,
                                                u16* __restrict__ out, int n) {
    int i = (blockIdx.x * 256 + threadIdx.x) * 4;
    if (i + 3 < n) {
        float4 v = *(const float4*)&in[i];
        ushort4 o;
        o.x = f2bf(v.x); o.y = f2bf(v.y); o.z = f2bf(v.z); o.w = f2bf(v.w);
        *(ushort4*)&out[i] = o;
    }
}

// ---------------------------------------------------------------------------
// bf16 MFMA GEMM: C[M,N] = A[M,K] @ W[N,K]^T. 128x128 tile, BK=32, 4 waves.
// LDS is frag-major: chunk (tile16_idx)*64 + lane holds T[row16 = lane&15]
// [k = (lane>>4)*8 .. +8] -> ds_read_b128 at base + lane*16 (canonical).
// EPI=0: plain fp32 store.  EPI=1: qkv scatter (bias, Q-scale, V transpose).
// ---------------------------------------------------------------------------
template<int EPI>
__global__ __launch_bounds__(256) void gemm_mfma(
    const u16* __restrict__ A, const u16* __restrict__ W,
    const float* __restrict__ bias, float* __restrict__ Cout,
    u16* __restrict__ Qb, u16* __restrict__ Kb, u16* __restrict__ Vt,
    int M, int N, int K)
{
    __shared__ __align__(16) u16 Af[8 * 64 * 8];   // 8 KB
    __shared__ __align__(16) u16 Bf[8 * 64 * 8];   // 8 KB
    const int t = threadIdx.x, l = t & 63, w = t >> 6;
    const int quad = l >> 4, ln = l & 15;
    const int wm = w >> 1, wn = w & 1;
    const int m0 = blockIdx.y * 128, n0 = blockIdx.x * 128;

    f32x4 acc[4][4];
#pragma unroll
    for (int i = 0; i < 4; ++i)
#pragma unroll
        for (int j = 0; j < 4; ++j)
#pragma unroll
            for (int r = 0; r < 4; ++r) acc[i][j][r] = 0.f;

    for (int k0 = 0; k0 < K; k0 += 32) {
#pragma unroll
        for (int i = 0; i < 2; ++i) {
            int mb = i * 4 + w;   // 16-row block 0..7
            async16(&A[(size_t)(m0 + mb * 16 + ln) * K + k0 + quad * 8],
                    &Af[(mb * 64 + l) * 8]);
            async16(&W[(size_t)(n0 + mb * 16 + ln) * K + k0 + quad * 8],
                    &Bf[(mb * 64 + l) * 8]);
        }
        __syncthreads();
        bf16x8 af[4], bfr[4];
#pragma unroll
        for (int x = 0; x < 4; ++x) {
            af[x]  = *(const bf16x8*)&Af[((wm * 4 + x) * 64 + l) * 8];
            bfr[x] = *(const bf16x8*)&Bf[((wn * 4 + x) * 64 + l) * 8];
        }
#pragma unroll
        for (int mt = 0; mt < 4; ++mt)
#pragma unroll
            for (int nt = 0; nt < 4; ++nt)
                acc[mt][nt] = __builtin_amdgcn_mfma_f32_16x16x32_bf16(
                    af[mt], bfr[nt], acc[mt][nt], 0, 0, 0);
        __syncthreads();
    }

    // C/D layout: col = lane&15, row = (lane>>4)*4 + reg   [verified m89/m91]
    if constexpr (EPI == 0) {
#pragma unroll
        for (int mt = 0; mt < 4; ++mt)
#pragma unroll
            for (int nt = 0; nt < 4; ++nt) {
                int col = n0 + (wn * 4 + nt) * 16 + ln;
#pragma unroll
                for (int r = 0; r < 4; ++r) {
                    int row = m0 + wm * 64 + mt * 16 + quad * 4 + r;
                    Cout[(size_t)row * N + col] = acc[mt][nt][r];
                }
            }
    } else {
        // fold 1/sqrt(128) * log2(e) into Q so softmax uses exp2
        const float kQS = 0.08838834764831845f * 1.44269504088896340f;
#pragma unroll
        for (int nt = 0; nt < 4; ++nt) {
            int col  = n0 + (wn * 4 + nt) * 16 + ln;
            int head = col / 384;
            int g    = col - head * 384;
            int sec  = g >> 7;        // 0=q 1=k 2=v (uniform per tile)
            int d    = g & 127;
            float bv = bias[col];
#pragma unroll
            for (int mt = 0; mt < 4; ++mt)
#pragma unroll
                for (int r = 0; r < 4; ++r) {
                    int tok = m0 + wm * 64 + mt * 16 + quad * 4 + r;
                    int s = tok >> 1, bb = tok & 1;
                    float v = acc[mt][nt][r] + bv;
                    if (sec == 0)
                        Qb[((size_t)(bb * NH_ + head) * S_LEN + s) * HN_ + d] = f2bf(v * kQS);
                    else if (sec == 1)
                        Kb[((size_t)(bb * NH_ + head) * S_LEN + s) * HN_ + d] = f2bf(v);
                    else  // V stored transposed [d][s] for PV B-fragments
                        Vt[((size_t)(bb * NH_ + head) * HN_ + d) * S_LEN + s] = f2bf(v);
                }
        }
    }
}

// ---------------------------------------------------------------------------
// MFMA flash attention. Block = 4 waves, 64 Q rows (wave w owns rows w*16..).
// K-tile = 64 tokens. Frag-major LDS staging via global_load_lds.
// Softmax state per lane: rows quad*4+r; row stats shfl-reduced over the
// 16-lane quad group; l kept lane-partial, reduced once at the end.
// ---------------------------------------------------------------------------
__global__ __launch_bounds__(256) void attn_mfma(
    const u16* __restrict__ Qb, const u16* __restrict__ Kb,
    const u16* __restrict__ Vt, u16* __restrict__ Ctx)
{
    __shared__ __align__(16) u16 Qf[16 * 64 * 8];   // 16 KB
    __shared__ __align__(16) u16 Kf[16 * 64 * 8];   // 16 KB
    __shared__ __align__(16) u16 Vf[16 * 64 * 8];   // 16 KB
    __shared__ __align__(16) u16 Ps[4][16][72];     // per-wave P, padded

    const int t = threadIdx.x, l = t & 63, w = t >> 6;
    const int quad = l >> 4, ln = l & 15;
    const int qt = (int)gridDim.x - 1 - (int)blockIdx.x;  // heavy tiles first
    const int n = blockIdx.y, b = blockIdx.z;
    const int q0 = qt * 64;
    const u16* Qh = Qb + (size_t)(b * NH_ + n) * S_LEN * HN_;
    const u16* Kh = Kb + (size_t)(b * NH_ + n) * S_LEN * HN_;
    const u16* Vh = Vt + (size_t)(b * NH_ + n) * HN_ * S_LEN;

    // stage Q tile once: chunk (mt*4+ks)*64+l -> mt=i, ks=w
#pragma unroll
    for (int i = 0; i < 4; ++i)
        async16(&Qh[(size_t)(q0 + i * 16 + ln) * HN_ + w * 32 + quad * 8],
                &Qf[((i * 4 + w) * 64 + l) * 8]);
    __syncthreads();
    bf16x8 qf[4];
#pragma unroll
    for (int ks = 0; ks < 4; ++ks)
        qf[ks] = *(const bf16x8*)&Qf[((w * 4 + ks) * 64 + l) * 8];

    float m_i[4], l_i[4];
    f32x4 acco[8];
#pragma unroll
    for (int r = 0; r < 4; ++r) { m_i[r] = -1e30f; l_i[r] = 0.f; }
#pragma unroll
    for (int dt = 0; dt < 8; ++dt)
#pragma unroll
        for (int r = 0; r < 4; ++r) acco[dt][r] = 0.f;

    for (int kt = 0; kt <= qt; ++kt) {
        // stage K (chunks: nt=i, ks=w) and V (chunks: dv=i*4+w -> dt,ks)
#pragma unroll
        for (int i = 0; i < 4; ++i) {
            async16(&Kh[(size_t)(kt * 64 + i * 16 + ln) * HN_ + w * 32 + quad * 8],
                    &Kf[((i * 4 + w) * 64 + l) * 8]);
            int dv = i * 4 + w, dt = dv >> 1, ks = dv & 1;
            async16(&Vh[(size_t)(dt * 16 + ln) * S_LEN + kt * 64 + ks * 32 + quad * 8],
                    &Vf[(dv * 64 + l) * 8]);
        }
        __syncthreads();

        // S = Q K^T : rows = wave's 16 q rows, cols = 64 k tokens
        f32x4 sc[4];
#pragma unroll
        for (int nt = 0; nt < 4; ++nt)
#pragma unroll
            for (int r = 0; r < 4; ++r) sc[nt][r] = 0.f;
#pragma unroll
        for (int nt = 0; nt < 4; ++nt)
#pragma unroll
            for (int ks = 0; ks < 4; ++ks) {
                bf16x8 kf = *(const bf16x8*)&Kf[((nt * 4 + ks) * 64 + l) * 8];
                sc[nt] = __builtin_amdgcn_mfma_f32_16x16x32_bf16(qf[ks], kf, sc[nt], 0, 0, 0);
            }

        if (kt == qt) {   // only the diagonal tile is partially masked
#pragma unroll
            for (int nt = 0; nt < 4; ++nt)
#pragma unroll
                for (int r = 0; r < 4; ++r)
                    if (nt * 16 + ln > w * 16 + quad * 4 + r) sc[nt][r] = -1e30f;
        }

        // online softmax (base-2; scale folded into Q)
        float corr[4];
#pragma unroll
        for (int r = 0; r < 4; ++r) {
            float mx = fmaxf(fmaxf(sc[0][r], sc[1][r]), fmaxf(sc[2][r], sc[3][r]));
            mx = fmaxf(mx, __shfl_xor(mx, 1));
            mx = fmaxf(mx, __shfl_xor(mx, 2));
            mx = fmaxf(mx, __shfl_xor(mx, 4));
            mx = fmaxf(mx, __shfl_xor(mx, 8));
            float mnew = fmaxf(m_i[r], mx);
            corr[r] = exp2f(m_i[r] - mnew);
            m_i[r] = mnew;
        }
#pragma unroll
        for (int r = 0; r < 4; ++r) {
            float ps = 0.f;
#pragma unroll
            for (int nt = 0; nt < 4; ++nt) {
                float p = exp2f(sc[nt][r] - m_i[r]);
                ps += p;
                Ps[w][quad * 4 + r][nt * 16 + ln] = f2bf(p);
            }
            l_i[r] = l_i[r] * corr[r] + ps;   // lane-partial l
        }

        // rescale O, then O += P @ V
#pragma unroll
        for (int dt = 0; dt < 8; ++dt)
#pragma unroll
            for (int r = 0; r < 4; ++r) acco[dt][r] *= corr[r];

        bf16x8 pf[2];
#pragma unroll
        for (int ks = 0; ks < 2; ++ks)
            pf[ks] = *(const bf16x8*)&Ps[w][ln][ks * 32 + quad * 8];
#pragma unroll
        for (int dt = 0; dt < 8; ++dt)
#pragma unroll
            for (int ks = 0; ks < 2; ++ks) {
                bf16x8 vf = *(const bf16x8*)&Vf[((dt * 2 + ks) * 64 + l) * 8];
                acco[dt] = __builtin_amdgcn_mfma_f32_16x16x32_bf16(pf[ks], vf, acco[dt], 0, 0, 0);
            }
        __syncthreads();   // all waves done with Kf/Vf before next stage
    }

    // finalize: reduce lane-partial l over the 16-lane quad group
#pragma unroll
    for (int r = 0; r < 4; ++r) {
        float s = l_i[r];
        s += __shfl_xor(s, 1);
        s += __shfl_xor(s, 2);
        s += __shfl_xor(s, 4);
        s += __shfl_xor(s, 8);
        l_i[r] = 1.f / s;
    }
#pragma unroll
    for (int dt = 0; dt < 8; ++dt)
#pragma unroll
        for (int r = 0; r < 4; ++r) {
            int srow = q0 + w * 16 + quad * 4 + r;
            Ctx[((size_t)(srow * B_SZ + b)) * H_DIM + n * HN_ + dt * 16 + ln] =
                f2bf(acco[dt][r] * l_i[r]);
        }
}

__global__ void copy_bias(const float* __restrict__ b_dense, float* __restrict__ out)
{
    int t = blockIdx.x * 256 + threadIdx.x;
    if (t < H_DIM) out[(size_t)M_TOK * H_DIM + t] = b_dense[t];
}

extern "C" void kernel_launch(void* const* d_in, const int* in_sizes, int n_in,
                              void* d_out, int out_size, void* d_ws, size_t ws_size,
                              hipStream_t stream)
{
    const float* hs      = (const float*)d_in[0];
    /* d_in[1] attention_mask: compile-time causal, ignored */
    const float* w_qkv   = (const float*)d_in[2];
    const float* b_qkv   = (const float*)d_in[3];
    const float* w_dense = (const float*)d_in[4];
    const float* b_dense = (const float*)d_in[5];
    float* out = (float*)d_out;

    u16* hs_bf = (u16*)d_ws;                           //  16.8 MB
    u16* wq_bf = hs_bf + (size_t)M_TOK * H_DIM;        //  25.2 MB
    u16* wd_bf = wq_bf + (size_t)NQKV * H_DIM;         //   8.4 MB
    u16* Qb    = wd_bf + (size_t)H_DIM * H_DIM;        //  16.8 MB  [b][n][s][d]
    u16* Kb    = Qb    + (size_t)M_TOK * H_DIM;        //  16.8 MB  [b][n][s][d]
    u16* Vt    = Kb    + (size_t)M_TOK * H_DIM;        //  16.8 MB  [b][n][d][s]
    u16* Ctx   = Vt    + (size_t)M_TOK * H_DIM;        //  16.8 MB  [s][b][h]

    cvt_bf16<<<(M_TOK * H_DIM) / 1024, 256, 0, stream>>>(hs, hs_bf, M_TOK * H_DIM);
    cvt_bf16<<<(NQKV * H_DIM) / 1024, 256, 0, stream>>>(w_qkv, wq_bf, NQKV * H_DIM);
    cvt_bf16<<<(H_DIM * H_DIM) / 1024, 256, 0, stream>>>(w_dense, wd_bf, H_DIM * H_DIM);

    gemm_mfma<1><<<dim3(NQKV / 128, M_TOK / 128), 256, 0, stream>>>(
        hs_bf, wq_bf, b_qkv, nullptr, Qb, Kb, Vt, M_TOK, NQKV, H_DIM);

    attn_mfma<<<dim3(S_LEN / 64, NH_, B_SZ), 256, 0, stream>>>(Qb, Kb, Vt, Ctx);

    gemm_mfma<0><<<dim3(H_DIM / 128, M_TOK / 128), 256, 0, stream>>>(
        Ctx, wd_bf, nullptr, out, nullptr, nullptr, nullptr, M_TOK, H_DIM, H_DIM);

    copy_bias<<<(H_DIM + 255) / 256, 256, 0, stream>>>(b_dense, out);
}